// Round 5
// baseline (285.681 us; speedup 1.0000x reference)
//
#include <hip/hip_runtime.h>
#include <hip/hip_bf16.h>
#include <math.h>

typedef __hip_bfloat16 bf16;
typedef __attribute__((ext_vector_type(8))) short bf16x8;
typedef __attribute__((ext_vector_type(4))) float f32x4;

#define GPTR(p) ((const __attribute__((address_space(1))) void*)(p))
#define LPTR(p) ((__attribute__((address_space(3))) void*)(p))

__device__ __forceinline__ float b2f(short s) {
  unsigned int u = ((unsigned int)(unsigned short)s) << 16;
  float f; __builtin_memcpy(&f, &u, 4); return f;
}

// ---------------------------------------------------------------------------
// Merged fp32 -> bf16 conversion for all 5 MFMA operand tensors (1 dispatch).
// ---------------------------------------------------------------------------
__global__ __launch_bounds__(256) void cvt_all(
    const float* __restrict__ x,    const float* __restrict__ w_in,
    const float* __restrict__ w_out,const float* __restrict__ w1,
    const float* __restrict__ w2,
    bf16* __restrict__ xb,   bf16* __restrict__ winb, bf16* __restrict__ woutb,
    bf16* __restrict__ w1b,  bf16* __restrict__ w2b)
{
  const int b = blockIdx.x;
  const float* in; bf16* out; int base;
  if      (b <  4096) { in = x;     out = xb;    base = 0; }
  else if (b <  7168) { in = w_in;  out = winb;  base = 4096; }
  else if (b <  8192) { in = w_out; out = woutb; base = 7168; }
  else if (b < 12288) { in = w1;    out = w1b;   base = 8192; }
  else                { in = w2;    out = w2b;   base = 12288; }
  const int i = ((b - base) * 256 + threadIdx.x) * 4;
  const float4 f = *(const float4*)(in + i);
  ushort4 u;
  u.x = __bfloat16_as_ushort(__float2bfloat16(f.x));
  u.y = __bfloat16_as_ushort(__float2bfloat16(f.y));
  u.z = __bfloat16_as_ushort(__float2bfloat16(f.z));
  u.w = __bfloat16_as_ushort(__float2bfloat16(f.w));
  *(ushort4*)(out + i) = u;
}

__device__ __forceinline__ float gelu_fast(float v) {
  const float u  = 1.5957691216f * (v + 0.044715f * v * v * v);
  const float e  = __expf(u);
  return v * e / (e + 1.0f);
}

// ---------------------------------------------------------------------------
// GEMM: C[M,N](bf16) = A[M,K](lda) * B[N,K]^T(ldb) [+ bias(fp32)] with
// optional fast-GELU epilogue and split-K via z. 128x128 tile, BK=64,
// 4 waves (2x2), 4x4 mfma_f32_16x16x32_bf16 per wave. XOR chunk swizzle ->
// 2-way LDS conflicts (free). __launch_bounds__(256,4) -> 4 blocks/CU.
// T1 XCD swizzle (m204) is ON for every call: r3-vs-r4 A/B showed removing
// it on square grids costs +6.6us on GEMM5 (54.0 vs 47.4) even though FETCH
// improves (37 vs 58 MB) — the kernel is latency- not HBM-bound, and
// XCD-private A-panels beat L2-resident B-panels on this 2-barrier loop.
// Epilogue ni-innermost (r3): WRITE_SIZE at ideal (52.9 -> 32.8 MB).
// ---------------------------------------------------------------------------
template<int GELU, int RESID>   // RESID: 0 none, 1 fp32, 2 bf16
__global__ __launch_bounds__(256, 4) void gemm_bt(
    const bf16* __restrict__ A, int lda,
    const bf16* __restrict__ B, int ldb,
    const float* __restrict__ bias,
    const void* __restrict__ Rv, int ldr,
    bf16* __restrict__ C, int ldc, long czstride,
    int M, int N, int kchunk)
{
  __shared__ __align__(16) bf16 As[128 * 64];
  __shared__ __align__(16) bf16 Bs[128 * 64];

  const int t    = threadIdx.x;
  const int lane = t & 63;
  const int w    = t >> 6;
  const int wm   = w >> 1;
  const int wn   = w & 1;
  const int lr   = lane & 15;
  const int lq   = lane >> 4;

  // T1: bijective XCD swizzle (m204); x fastest within each XCD's wid range.
  const int gx   = gridDim.x, gy = gridDim.y;
  const int nwg  = gx * gy * gridDim.z;
  const int orig = blockIdx.x + gx * (blockIdx.y + gy * blockIdx.z);
  const int qq   = nwg >> 3, rr = nwg & 7;
  const int xcd  = orig & 7;
  const int wid  = (xcd < rr ? xcd * (qq + 1) : rr * (qq + 1) + (xcd - rr) * qq)
                 + (orig >> 3);
  const int n0 = (wid % gx) * 128;
  const int m0 = ((wid / gx) % gy) * 128;
  const int kz = wid / (gx * gy);

  A += (size_t)kz * kchunk;
  B += (size_t)kz * kchunk;
  C += (size_t)kz * czstride;

  f32x4 acc[4][4];
  #pragma unroll
  for (int mi = 0; mi < 4; ++mi)
    #pragma unroll
    for (int ni = 0; ni < 4; ++ni)
      acc[mi][ni] = (f32x4){0.f, 0.f, 0.f, 0.f};

  const int wbase = (t & ~63) * 8;

  for (int k0 = 0; k0 < kchunk; k0 += 64) {
    #pragma unroll
    for (int it = 0; it < 4; ++it) {
      const int c    = it * 256 + t;
      const int row  = c >> 3;
      const int csw  = ((c & 7) ^ (row & 7)) << 3;
      const bf16* ga = A + (size_t)(m0 + row) * lda + k0 + csw;
      const bf16* gb = B + (size_t)(n0 + row) * ldb + k0 + csw;
      __builtin_amdgcn_global_load_lds(GPTR(ga), LPTR(&As[it * 2048 + wbase]), 16, 0, 0);
      __builtin_amdgcn_global_load_lds(GPTR(gb), LPTR(&Bs[it * 2048 + wbase]), 16, 0, 0);
    }
    __syncthreads();

    #pragma unroll
    for (int ks = 0; ks < 2; ++ks) {
      const int swz = (((ks * 4 + lq) ^ (lr & 7)) << 3);
      bf16x8 af[4], bfr[4];
      #pragma unroll
      for (int mi = 0; mi < 4; ++mi)
        af[mi] = *(const bf16x8*)&As[(wm * 64 + mi * 16 + lr) * 64 + swz];
      #pragma unroll
      for (int ni = 0; ni < 4; ++ni)
        bfr[ni] = *(const bf16x8*)&Bs[(wn * 64 + ni * 16 + lr) * 64 + swz];
      #pragma unroll
      for (int mi = 0; mi < 4; ++mi)
        #pragma unroll
        for (int ni = 0; ni < 4; ++ni)
          acc[mi][ni] = __builtin_amdgcn_mfma_f32_16x16x32_bf16(af[mi], bfr[ni], acc[mi][ni], 0, 0, 0);
    }
    __syncthreads();
  }

  // Epilogue, ni innermost: per (mi,i) the 4 stores cover one row's 128
  // contiguous cols back-to-back (write-combine friendly).
  float bvv[4];
  #pragma unroll
  for (int ni = 0; ni < 4; ++ni)
    bvv[ni] = bias ? bias[n0 + wn * 64 + ni * 16 + lr] : 0.f;
  #pragma unroll
  for (int mi = 0; mi < 4; ++mi) {
    const int rowb = m0 + wm * 64 + mi * 16 + lq * 4;
    #pragma unroll
    for (int i = 0; i < 4; ++i) {
      const size_t rb = (size_t)(rowb + i);
      #pragma unroll
      for (int ni = 0; ni < 4; ++ni) {
        const int col = n0 + wn * 64 + ni * 16 + lr;
        float v = acc[mi][ni][i] + bvv[ni];
        if (GELU) v = gelu_fast(v);
        if (RESID == 1) v += ((const float*)Rv)[rb * ldr + col];
        if (RESID == 2) v += __bfloat162float(((const bf16*)Rv)[rb * ldr + col]);
        C[rb * ldc + col] = __float2bfloat16(v);
      }
    }
  }
}

// ---------------------------------------------------------------------------
// Window-5 causal attention, one WAVE per token. lane = h*4 + c. Scores stay
// register-local; in-place into q-cols (wave t is the sole reader of q[t]).
// ---------------------------------------------------------------------------
__global__ __launch_bounds__(256) void attn_win(bf16* __restrict__ qkv)
{
  const int lane = threadIdx.x & 63;
  const int tk   = blockIdx.x * 4 + (threadIdx.x >> 6);   // token 0..4095
  const int s    = tk & 2047;                             // pos in sequence
  const int doff = (lane >> 2) * 64 + (lane & 3) * 16;    // h*64 + c*16

  const size_t row = (size_t)tk * 3072;

  bf16x8 qa = *(const bf16x8*)&qkv[row + doff];
  bf16x8 qb = *(const bf16x8*)&qkv[row + doff + 8];
  float qf[16];
  #pragma unroll
  for (int e = 0; e < 8; ++e) { qf[e] = b2f(qa[e]); qf[8 + e] = b2f(qb[e]); }

  const int W = (s + 1 < 5) ? (s + 1) : 5;
  float p[5];
  #pragma unroll
  for (int j = 0; j < 5; ++j) {
    const int jc = (j < W) ? j : 0;                       // clamped (valid addr)
    const size_t kr = row - (size_t)jc * 3072 + 1024;
    bf16x8 ka = *(const bf16x8*)&qkv[kr + doff];
    bf16x8 kb = *(const bf16x8*)&qkv[kr + doff + 8];
    float d = 0.f;
    #pragma unroll
    for (int e = 0; e < 8; ++e) d += qf[e] * b2f(ka[e]);
    #pragma unroll
    for (int e = 0; e < 8; ++e) d += qf[8 + e] * b2f(kb[e]);
    d += __shfl_xor(d, 1);
    d += __shfl_xor(d, 2);
    p[j] = (j < W) ? d * 0.125f : -1e30f;                 // 1/sqrt(64); mask
  }

  float mx = fmaxf(fmaxf(fmaxf(p[0], p[1]), fmaxf(p[2], p[3])), p[4]);
  float sum = 0.f;
  #pragma unroll
  for (int j = 0; j < 5; ++j) { p[j] = __expf(p[j] - mx); sum += p[j]; }
  const float inv = 1.f / sum;

  float o[16];
  #pragma unroll
  for (int e = 0; e < 16; ++e) o[e] = 0.f;
  #pragma unroll
  for (int j = 0; j < 5; ++j) {
    const int jc = (j < W) ? j : 0;
    const size_t vr = row - (size_t)jc * 3072 + 2048;
    bf16x8 va = *(const bf16x8*)&qkv[vr + doff];
    bf16x8 vb = *(const bf16x8*)&qkv[vr + doff + 8];
    #pragma unroll
    for (int e = 0; e < 8; ++e) { o[e] += p[j] * b2f(va[e]); o[8 + e] += p[j] * b2f(vb[e]); }
  }

  bf16x8 oa, ob;
  #pragma unroll
  for (int e = 0; e < 8; ++e) {
    oa[e] = (short)__bfloat16_as_ushort(__float2bfloat16(o[e] * inv));
    ob[e] = (short)__bfloat16_as_ushort(__float2bfloat16(o[8 + e] * inv));
  }
  *(bf16x8*)&qkv[row + doff]     = oa;
  *(bf16x8*)&qkv[row + doff + 8] = ob;
}

// ---------------------------------------------------------------------------
// Fused split-K reduce + residual + bias + LayerNorm over dim=1024.
// Lane-contiguous partition (G13): lane L owns elems [16L,16L+16) of the row,
// loaded as 2x bf16x8 (16 B/lane/inst) instead of scalar bf16 (2 B/lane).
// The 64-lane shfl reductions are partition-agnostic.
// ---------------------------------------------------------------------------
template<int OUTF32, int RESBF16>
__global__ __launch_bounds__(256) void ln_fuse(
    const bf16* __restrict__ P0, const bf16* __restrict__ P1, int ldp,
    const void* __restrict__ Rv,
    const float* __restrict__ bias,
    const float* __restrict__ g, const float* __restrict__ bt,
    void* __restrict__ outv)
{
  const int tk   = blockIdx.x * 4 + (threadIdx.x >> 6);
  const int lane = threadIdx.x & 63;
  const int e0   = lane * 16;                     // position within the row
  const size_t bp = (size_t)tk * ldp + e0;
  const size_t bo = (size_t)tk * 1024 + e0;

  const bf16x8 p0a = *(const bf16x8*)&P0[bp];
  const bf16x8 p0b = *(const bf16x8*)&P0[bp + 8];
  const bf16x8 p1a = *(const bf16x8*)&P1[bp];
  const bf16x8 p1b = *(const bf16x8*)&P1[bp + 8];

  float v[16];
  float sum = 0.f;
  if (RESBF16) {
    const bf16* R = (const bf16*)Rv;
    const bf16x8 ra = *(const bf16x8*)&R[bo];
    const bf16x8 rb = *(const bf16x8*)&R[bo + 8];
    #pragma unroll
    for (int i = 0; i < 8; ++i) {
      v[i]     = b2f(p0a[i]) + b2f(p1a[i]) + bias[e0 + i]     + b2f(ra[i]);
      v[8 + i] = b2f(p0b[i]) + b2f(p1b[i]) + bias[e0 + 8 + i] + b2f(rb[i]);
      sum += v[i] + v[8 + i];
    }
  } else {
    const float* R = (const float*)Rv;
    #pragma unroll
    for (int q = 0; q < 4; ++q) {
      const float4 r = *(const float4*)&R[bo + q * 4];
      const float rr[4] = {r.x, r.y, r.z, r.w};
      #pragma unroll
      for (int j = 0; j < 4; ++j) {
        const int i = q * 4 + j;
        const float pv = (i < 8) ? b2f(p0a[i]) + b2f(p1a[i])
                                 : b2f(p0b[i - 8]) + b2f(p1b[i - 8]);
        v[i] = pv + bias[e0 + i] + rr[j];
        sum += v[i];
      }
    }
  }
  #pragma unroll
  for (int d = 1; d < 64; d <<= 1) sum += __shfl_xor(sum, d);
  const float mu = sum * (1.f / 1024.f);

  float sq = 0.f;
  #pragma unroll
  for (int i = 0; i < 16; ++i) { const float dv = v[i] - mu; sq += dv * dv; }
  #pragma unroll
  for (int d = 1; d < 64; d <<= 1) sq += __shfl_xor(sq, d);
  const float rstd = rsqrtf(sq * (1.f / 1024.f) + 1e-5f);

  if (OUTF32) {
    float* o = (float*)outv;
    #pragma unroll
    for (int q = 0; q < 4; ++q) {
      float4 ov;
      ov.x = (v[q*4+0] - mu) * rstd * g[e0 + q*4+0] + bt[e0 + q*4+0];
      ov.y = (v[q*4+1] - mu) * rstd * g[e0 + q*4+1] + bt[e0 + q*4+1];
      ov.z = (v[q*4+2] - mu) * rstd * g[e0 + q*4+2] + bt[e0 + q*4+2];
      ov.w = (v[q*4+3] - mu) * rstd * g[e0 + q*4+3] + bt[e0 + q*4+3];
      *(float4*)&o[bo + q * 4] = ov;
    }
  } else {
    bf16* o = (bf16*)outv;
    bf16x8 oa, ob;
    #pragma unroll
    for (int i = 0; i < 8; ++i) {
      oa[i] = (short)__bfloat16_as_ushort(__float2bfloat16(
                  (v[i] - mu) * rstd * g[e0 + i] + bt[e0 + i]));
      ob[i] = (short)__bfloat16_as_ushort(__float2bfloat16(
                  (v[8 + i] - mu) * rstd * g[e0 + 8 + i] + bt[e0 + 8 + i]));
    }
    *(bf16x8*)&o[bo]     = oa;
    *(bf16x8*)&o[bo + 8] = ob;
  }
}

// ---------------------------------------------------------------------------
// WS layout (72 MB):
//   0        : qkv [4096,3072] bf16 / phase2: h [4096,4096]
//   33554432 : x_b [4096,1024] -> GEMM6 partial P0
//   41943040 : x1_b [4096,1024]
//   50331648 : w1_b [4096,1024] -> GEMM6 partial P1
//   58720256 : w2_b [1024,4096]
//   67108864 : w_in_b [3072,1024]
//   73400320 : w_out_b [1024,1024]
// ---------------------------------------------------------------------------
extern "C" void kernel_launch(void* const* d_in, const int* in_sizes, int n_in,
                              void* d_out, int out_size, void* d_ws, size_t ws_size,
                              hipStream_t stream)
{
  const float* x     = (const float*)d_in[0];
  const float* w_in  = (const float*)d_in[1];
  const float* b_in  = (const float*)d_in[2];
  const float* w_out = (const float*)d_in[3];
  const float* b_out = (const float*)d_in[4];
  const float* ln1_g = (const float*)d_in[5];
  const float* ln1_b = (const float*)d_in[6];
  const float* ln2_g = (const float*)d_in[7];
  const float* ln2_b = (const float*)d_in[8];
  const float* w1    = (const float*)d_in[9];
  const float* b1    = (const float*)d_in[10];
  const float* w2    = (const float*)d_in[11];
  const float* b2    = (const float*)d_in[12];
  float* out = (float*)d_out;

  char* ws = (char*)d_ws;
  bf16* qkv     = (bf16*)(ws);
  bf16* h       = (bf16*)(ws);
  bf16* x_b     = (bf16*)(ws + 33554432);
  bf16* x1_b    = (bf16*)(ws + 41943040);
  bf16* w1_b    = (bf16*)(ws + 50331648);
  bf16* w2_b    = (bf16*)(ws + 58720256);
  bf16* w_in_b  = (bf16*)(ws + 67108864);
  bf16* w_out_b = (bf16*)(ws + 73400320);
  bf16* P0      = x_b;
  bf16* P1      = w1_b;

  const dim3 blk(256);

  // 0) fp32 -> bf16 operand conversion (single dispatch)
  cvt_all<<<dim3(16384), blk, 0, stream>>>(x, w_in, w_out, w1, w2,
                                           x_b, w_in_b, w_out_b, w1_b, w2_b);

  // 1) qkv = x @ w_in^T + b_in                      [4096,3072]
  gemm_bt<0,0><<<dim3(24, 32, 1), blk, 0, stream>>>(
      x_b, 1024, w_in_b, 1024, b_in, nullptr, 0, qkv, 3072, 0, 4096, 3072, 1024);
  // 2) windowed causal attention, in-place into q-cols (wave per token)
  attn_win<<<dim3(1024), blk, 0, stream>>>(qkv);
  // 3) split-K=2: k-cols/v-cols = attn @ w_out^T partials
  gemm_bt<0,0><<<dim3(8, 32, 2), blk, 0, stream>>>(
      qkv, 3072, w_out_b, 1024, nullptr, nullptr, 0,
      qkv + 1024, 3072, 1024, 4096, 1024, 512);
  // 4) x1_b = LN(x + P0 + P1 + b_out)
  ln_fuse<0,0><<<dim3(1024), blk, 0, stream>>>(
      qkv + 1024, qkv + 2048, 3072, x, b_out, ln1_g, ln1_b, x1_b);
  // 5) h = gelu(x1 @ w1^T + b1)                     [4096,4096]
  gemm_bt<1,0><<<dim3(32, 32, 1), blk, 0, stream>>>(
      x1_b, 1024, w1_b, 1024, b1, nullptr, 0, h, 4096, 0, 4096, 4096, 1024);
  // 6) split-K=2: P0/P1 = h @ w2^T partials
  gemm_bt<0,0><<<dim3(8, 32, 2), blk, 0, stream>>>(
      h, 4096, w2_b, 4096, nullptr, nullptr, 0,
      P0, 1024, 8388608, 4096, 1024, 2048);
  // 7) out(fp32) = LN(x1 + P0 + P1 + b2)
  ln_fuse<1,1><<<dim3(1024), blk, 0, stream>>>(
      P0, P1, 1024, x1_b, b2, ln2_g, ln2_b, out);
}

// Round 6
// 279.138 us; speedup vs baseline: 1.0234x; 1.0234x over previous
//
#include <hip/hip_runtime.h>
#include <hip/hip_bf16.h>
#include <math.h>

typedef __hip_bfloat16 bf16;
typedef __attribute__((ext_vector_type(8))) short bf16x8;
typedef __attribute__((ext_vector_type(4))) short bf16x4;
typedef __attribute__((ext_vector_type(4))) float f32x4;

#define GPTR(p) ((const __attribute__((address_space(1))) void*)(p))
#define LPTR(p) ((__attribute__((address_space(3))) void*)(p))

__device__ __forceinline__ float b2f(short s) {
  unsigned int u = ((unsigned int)(unsigned short)s) << 16;
  float f; __builtin_memcpy(&f, &u, 4); return f;
}

// ---------------------------------------------------------------------------
// Merged fp32 -> bf16 conversion for all 5 MFMA operand tensors (1 dispatch).
// ---------------------------------------------------------------------------
__global__ __launch_bounds__(256) void cvt_all(
    const float* __restrict__ x,    const float* __restrict__ w_in,
    const float* __restrict__ w_out,const float* __restrict__ w1,
    const float* __restrict__ w2,
    bf16* __restrict__ xb,   bf16* __restrict__ winb, bf16* __restrict__ woutb,
    bf16* __restrict__ w1b,  bf16* __restrict__ w2b)
{
  const int b = blockIdx.x;
  const float* in; bf16* out; int base;
  if      (b <  4096) { in = x;     out = xb;    base = 0; }
  else if (b <  7168) { in = w_in;  out = winb;  base = 4096; }
  else if (b <  8192) { in = w_out; out = woutb; base = 7168; }
  else if (b < 12288) { in = w1;    out = w1b;   base = 8192; }
  else                { in = w2;    out = w2b;   base = 12288; }
  const int i = ((b - base) * 256 + threadIdx.x) * 4;
  const float4 f = *(const float4*)(in + i);
  ushort4 u;
  u.x = __bfloat16_as_ushort(__float2bfloat16(f.x));
  u.y = __bfloat16_as_ushort(__float2bfloat16(f.y));
  u.z = __bfloat16_as_ushort(__float2bfloat16(f.z));
  u.w = __bfloat16_as_ushort(__float2bfloat16(f.w));
  *(ushort4*)(out + i) = u;
}

__device__ __forceinline__ float gelu_fast(float v) {
  const float u  = 1.5957691216f * (v + 0.044715f * v * v * v);
  const float e  = __expf(u);
  return v * e / (e + 1.0f);
}

// ---------------------------------------------------------------------------
// GEMM: C[M,N](bf16) = A[M,K](lda) * B[N,K]^T(ldb) [+ bias(fp32)] with
// optional fast-GELU epilogue and split-K via z. 128x128 tile, BK=64,
// 4 waves (2x2), 4x4 mfma_f32_16x16x32_bf16 per wave. XOR chunk swizzle ->
// 2-way LDS conflicts (free). __launch_bounds__(256,4) -> 4 blocks/CU.
// T1 XCD swizzle (m204) ON for every call: r3/r4/r5 A/B showed removing it
// costs +6.6us on GEMM5 even though FETCH improves (37 vs 58 MB) — the
// kernel is latency- not HBM-bound; XCD-private A-panels win.
// Epilogue ni-innermost (r3): WRITE_SIZE at ideal (52.9 -> 32.8 MB).
// ---------------------------------------------------------------------------
template<int GELU, int RESID>   // RESID: 0 none, 1 fp32, 2 bf16
__global__ __launch_bounds__(256, 4) void gemm_bt(
    const bf16* __restrict__ A, int lda,
    const bf16* __restrict__ B, int ldb,
    const float* __restrict__ bias,
    const void* __restrict__ Rv, int ldr,
    bf16* __restrict__ C, int ldc, long czstride,
    int M, int N, int kchunk)
{
  __shared__ __align__(16) bf16 As[128 * 64];
  __shared__ __align__(16) bf16 Bs[128 * 64];

  const int t    = threadIdx.x;
  const int lane = t & 63;
  const int w    = t >> 6;
  const int wm   = w >> 1;
  const int wn   = w & 1;
  const int lr   = lane & 15;
  const int lq   = lane >> 4;

  // T1: bijective XCD swizzle (m204); x fastest within each XCD's wid range.
  const int gx   = gridDim.x, gy = gridDim.y;
  const int nwg  = gx * gy * gridDim.z;
  const int orig = blockIdx.x + gx * (blockIdx.y + gy * blockIdx.z);
  const int qq   = nwg >> 3, rr = nwg & 7;
  const int xcd  = orig & 7;
  const int wid  = (xcd < rr ? xcd * (qq + 1) : rr * (qq + 1) + (xcd - rr) * qq)
                 + (orig >> 3);
  const int n0 = (wid % gx) * 128;
  const int m0 = ((wid / gx) % gy) * 128;
  const int kz = wid / (gx * gy);

  A += (size_t)kz * kchunk;
  B += (size_t)kz * kchunk;
  C += (size_t)kz * czstride;

  f32x4 acc[4][4];
  #pragma unroll
  for (int mi = 0; mi < 4; ++mi)
    #pragma unroll
    for (int ni = 0; ni < 4; ++ni)
      acc[mi][ni] = (f32x4){0.f, 0.f, 0.f, 0.f};

  const int wbase = (t & ~63) * 8;

  for (int k0 = 0; k0 < kchunk; k0 += 64) {
    #pragma unroll
    for (int it = 0; it < 4; ++it) {
      const int c    = it * 256 + t;
      const int row  = c >> 3;
      const int csw  = ((c & 7) ^ (row & 7)) << 3;
      const bf16* ga = A + (size_t)(m0 + row) * lda + k0 + csw;
      const bf16* gb = B + (size_t)(n0 + row) * ldb + k0 + csw;
      __builtin_amdgcn_global_load_lds(GPTR(ga), LPTR(&As[it * 2048 + wbase]), 16, 0, 0);
      __builtin_amdgcn_global_load_lds(GPTR(gb), LPTR(&Bs[it * 2048 + wbase]), 16, 0, 0);
    }
    __syncthreads();

    #pragma unroll
    for (int ks = 0; ks < 2; ++ks) {
      const int swz = (((ks * 4 + lq) ^ (lr & 7)) << 3);
      bf16x8 af[4], bfr[4];
      #pragma unroll
      for (int mi = 0; mi < 4; ++mi)
        af[mi] = *(const bf16x8*)&As[(wm * 64 + mi * 16 + lr) * 64 + swz];
      #pragma unroll
      for (int ni = 0; ni < 4; ++ni)
        bfr[ni] = *(const bf16x8*)&Bs[(wn * 64 + ni * 16 + lr) * 64 + swz];
      #pragma unroll
      for (int mi = 0; mi < 4; ++mi)
        #pragma unroll
        for (int ni = 0; ni < 4; ++ni)
          acc[mi][ni] = __builtin_amdgcn_mfma_f32_16x16x32_bf16(af[mi], bfr[ni], acc[mi][ni], 0, 0, 0);
    }
    __syncthreads();
  }

  // Epilogue, ni innermost: per (mi,i) the 4 stores cover one row's 128
  // contiguous cols back-to-back (write-combine friendly).
  float bvv[4];
  #pragma unroll
  for (int ni = 0; ni < 4; ++ni)
    bvv[ni] = bias ? bias[n0 + wn * 64 + ni * 16 + lr] : 0.f;
  #pragma unroll
  for (int mi = 0; mi < 4; ++mi) {
    const int rowb = m0 + wm * 64 + mi * 16 + lq * 4;
    #pragma unroll
    for (int i = 0; i < 4; ++i) {
      const size_t rb = (size_t)(rowb + i);
      #pragma unroll
      for (int ni = 0; ni < 4; ++ni) {
        const int col = n0 + wn * 64 + ni * 16 + lr;
        float v = acc[mi][ni][i] + bvv[ni];
        if (GELU) v = gelu_fast(v);
        if (RESID == 1) v += ((const float*)Rv)[rb * ldr + col];
        if (RESID == 2) v += __bfloat162float(((const bf16*)Rv)[rb * ldr + col]);
        C[rb * ldc + col] = __float2bfloat16(v);
      }
    }
  }
}

// ---------------------------------------------------------------------------
// Window-5 causal attention, one WAVE per token. lane = h*4 + c. Scores stay
// register-local; in-place into q-cols (wave t is the sole reader of q[t]).
// XCD grouping (m204, 1024 % 8 == 0 so the simple form is bijective):
// adjacent blocks (= adjacent tokens) land on the same XCD, making the
// 5-token window's K/V row reuse L2-local instead of cross-XCD.
// ---------------------------------------------------------------------------
__global__ __launch_bounds__(256) void attn_win(bf16* __restrict__ qkv)
{
  const int lane = threadIdx.x & 63;
  const int nb   = gridDim.x;                    // 1024, divisible by 8
  const int bq   = nb >> 3;
  const int bid  = (blockIdx.x & 7) * bq + (blockIdx.x >> 3);
  const int tk   = bid * 4 + (threadIdx.x >> 6);          // token 0..4095
  const int s    = tk & 2047;                             // pos in sequence
  const int doff = (lane >> 2) * 64 + (lane & 3) * 16;    // h*64 + c*16

  const size_t row = (size_t)tk * 3072;

  bf16x8 qa = *(const bf16x8*)&qkv[row + doff];
  bf16x8 qb = *(const bf16x8*)&qkv[row + doff + 8];
  float qf[16];
  #pragma unroll
  for (int e = 0; e < 8; ++e) { qf[e] = b2f(qa[e]); qf[8 + e] = b2f(qb[e]); }

  const int W = (s + 1 < 5) ? (s + 1) : 5;
  float p[5];
  #pragma unroll
  for (int j = 0; j < 5; ++j) {
    const int jc = (j < W) ? j : 0;                       // clamped (valid addr)
    const size_t kr = row - (size_t)jc * 3072 + 1024;
    bf16x8 ka = *(const bf16x8*)&qkv[kr + doff];
    bf16x8 kb = *(const bf16x8*)&qkv[kr + doff + 8];
    float d = 0.f;
    #pragma unroll
    for (int e = 0; e < 8; ++e) d += qf[e] * b2f(ka[e]);
    #pragma unroll
    for (int e = 0; e < 8; ++e) d += qf[8 + e] * b2f(kb[e]);
    d += __shfl_xor(d, 1);
    d += __shfl_xor(d, 2);
    p[j] = (j < W) ? d * 0.125f : -1e30f;                 // 1/sqrt(64); mask
  }

  float mx = fmaxf(fmaxf(fmaxf(p[0], p[1]), fmaxf(p[2], p[3])), p[4]);
  float sum = 0.f;
  #pragma unroll
  for (int j = 0; j < 5; ++j) { p[j] = __expf(p[j] - mx); sum += p[j]; }
  const float inv = 1.f / sum;

  float o[16];
  #pragma unroll
  for (int e = 0; e < 16; ++e) o[e] = 0.f;
  #pragma unroll
  for (int j = 0; j < 5; ++j) {
    const int jc = (j < W) ? j : 0;
    const size_t vr = row - (size_t)jc * 3072 + 2048;
    bf16x8 va = *(const bf16x8*)&qkv[vr + doff];
    bf16x8 vb = *(const bf16x8*)&qkv[vr + doff + 8];
    #pragma unroll
    for (int e = 0; e < 8; ++e) { o[e] += p[j] * b2f(va[e]); o[8 + e] += p[j] * b2f(vb[e]); }
  }

  bf16x8 oa, ob;
  #pragma unroll
  for (int e = 0; e < 8; ++e) {
    oa[e] = (short)__bfloat16_as_ushort(__float2bfloat16(o[e] * inv));
    ob[e] = (short)__bfloat16_as_ushort(__float2bfloat16(o[8 + e] * inv));
  }
  *(bf16x8*)&qkv[row + doff]     = oa;
  *(bf16x8*)&qkv[row + doff + 8] = ob;
}

// ---------------------------------------------------------------------------
// Fused split-K reduce + residual + bias + LayerNorm over dim=1024.
// Partition (r6): lane L owns elems {256q + 4L + j, q,j in 0..3}. EVERY
// array access is then a fully-coalesced 64-lane vector op: bf16 as bf16x4
// (8 B/lane, 512 B/inst), fp32 + bias/g/bt as float4 (16 B/lane, 1 KB/inst).
// r5's lane-contiguous variant scattered bias/g/bt at stride 64 B (32 lines
// per scalar instruction) and cost ~+11 us — do not regress to it.
// Reductions are partition-agnostic (full 64-lane shfl butterflies).
// ---------------------------------------------------------------------------
template<int OUTF32, int RESBF16>
__global__ __launch_bounds__(256) void ln_fuse(
    const bf16* __restrict__ P0, const bf16* __restrict__ P1, int ldp,
    const void* __restrict__ Rv,
    const float* __restrict__ bias,
    const float* __restrict__ g, const float* __restrict__ bt,
    void* __restrict__ outv)
{
  const int tk   = blockIdx.x * 4 + (threadIdx.x >> 6);
  const int lane = threadIdx.x & 63;
  const int e0   = lane * 4;                      // chunk base within 256-span
  const size_t bp = (size_t)tk * ldp + e0;
  const size_t bo = (size_t)tk * 1024 + e0;

  float v[16];
  float sum = 0.f;
  #pragma unroll
  for (int q = 0; q < 4; ++q) {
    const bf16x4 p0 = *(const bf16x4*)&P0[bp + 256 * q];
    const bf16x4 p1 = *(const bf16x4*)&P1[bp + 256 * q];
    const float4 bs = *(const float4*)&bias[e0 + 256 * q];
    const float bsa[4] = {bs.x, bs.y, bs.z, bs.w};
    float ra[4];
    if (RESBF16) {
      const bf16x4 r = *(const bf16x4*)&((const bf16*)Rv)[bo + 256 * q];
      #pragma unroll
      for (int j = 0; j < 4; ++j) ra[j] = b2f(r[j]);
    } else {
      const float4 r = *(const float4*)&((const float*)Rv)[bo + 256 * q];
      ra[0] = r.x; ra[1] = r.y; ra[2] = r.z; ra[3] = r.w;
    }
    #pragma unroll
    for (int j = 0; j < 4; ++j) {
      const float tv = b2f(p0[j]) + b2f(p1[j]) + bsa[j] + ra[j];
      v[q * 4 + j] = tv;
      sum += tv;
    }
  }
  #pragma unroll
  for (int d = 1; d < 64; d <<= 1) sum += __shfl_xor(sum, d);
  const float mu = sum * (1.f / 1024.f);

  float sq = 0.f;
  #pragma unroll
  for (int i = 0; i < 16; ++i) { const float dv = v[i] - mu; sq += dv * dv; }
  #pragma unroll
  for (int d = 1; d < 64; d <<= 1) sq += __shfl_xor(sq, d);
  const float rstd = rsqrtf(sq * (1.f / 1024.f) + 1e-5f);

  #pragma unroll
  for (int q = 0; q < 4; ++q) {
    const float4 gv = *(const float4*)&g[e0 + 256 * q];
    const float4 bv = *(const float4*)&bt[e0 + 256 * q];
    const float ga[4] = {gv.x, gv.y, gv.z, gv.w};
    const float ba[4] = {bv.x, bv.y, bv.z, bv.w};
    float ov[4];
    #pragma unroll
    for (int j = 0; j < 4; ++j)
      ov[j] = (v[q * 4 + j] - mu) * rstd * ga[j] + ba[j];
    if (OUTF32) {
      float4 f; f.x = ov[0]; f.y = ov[1]; f.z = ov[2]; f.w = ov[3];
      *(float4*)&((float*)outv)[bo + 256 * q] = f;
    } else {
      bf16x4 ob;
      #pragma unroll
      for (int j = 0; j < 4; ++j)
        ob[j] = (short)__bfloat16_as_ushort(__float2bfloat16(ov[j]));
      *(bf16x4*)&((bf16*)outv)[bo + 256 * q] = ob;
    }
  }
}

// ---------------------------------------------------------------------------
// WS layout (72 MB):
//   0        : qkv [4096,3072] bf16 / phase2: h [4096,4096]
//   33554432 : x_b [4096,1024] -> GEMM6 partial P0
//   41943040 : x1_b [4096,1024]
//   50331648 : w1_b [4096,1024] -> GEMM6 partial P1
//   58720256 : w2_b [1024,4096]
//   67108864 : w_in_b [3072,1024]
//   73400320 : w_out_b [1024,1024]
// ---------------------------------------------------------------------------
extern "C" void kernel_launch(void* const* d_in, const int* in_sizes, int n_in,
                              void* d_out, int out_size, void* d_ws, size_t ws_size,
                              hipStream_t stream)
{
  const float* x     = (const float*)d_in[0];
  const float* w_in  = (const float*)d_in[1];
  const float* b_in  = (const float*)d_in[2];
  const float* w_out = (const float*)d_in[3];
  const float* b_out = (const float*)d_in[4];
  const float* ln1_g = (const float*)d_in[5];
  const float* ln1_b = (const float*)d_in[6];
  const float* ln2_g = (const float*)d_in[7];
  const float* ln2_b = (const float*)d_in[8];
  const float* w1    = (const float*)d_in[9];
  const float* b1    = (const float*)d_in[10];
  const float* w2    = (const float*)d_in[11];
  const float* b2    = (const float*)d_in[12];
  float* out = (float*)d_out;

  char* ws = (char*)d_ws;
  bf16* qkv     = (bf16*)(ws);
  bf16* h       = (bf16*)(ws);
  bf16* x_b     = (bf16*)(ws + 33554432);
  bf16* x1_b    = (bf16*)(ws + 41943040);
  bf16* w1_b    = (bf16*)(ws + 50331648);
  bf16* w2_b    = (bf16*)(ws + 58720256);
  bf16* w_in_b  = (bf16*)(ws + 67108864);
  bf16* w_out_b = (bf16*)(ws + 73400320);
  bf16* P0      = x_b;
  bf16* P1      = w1_b;

  const dim3 blk(256);

  // 0) fp32 -> bf16 operand conversion (single dispatch)
  cvt_all<<<dim3(16384), blk, 0, stream>>>(x, w_in, w_out, w1, w2,
                                           x_b, w_in_b, w_out_b, w1_b, w2_b);

  // 1) qkv = x @ w_in^T + b_in                      [4096,3072]
  gemm_bt<0,0><<<dim3(24, 32, 1), blk, 0, stream>>>(
      x_b, 1024, w_in_b, 1024, b_in, nullptr, 0, qkv, 3072, 0, 4096, 3072, 1024);
  // 2) windowed causal attention, in-place into q-cols (wave per token)
  attn_win<<<dim3(1024), blk, 0, stream>>>(qkv);
  // 3) split-K=2: k-cols/v-cols = attn @ w_out^T partials
  gemm_bt<0,0><<<dim3(8, 32, 2), blk, 0, stream>>>(
      qkv, 3072, w_out_b, 1024, nullptr, nullptr, 0,
      qkv + 1024, 3072, 1024, 4096, 1024, 512);
  // 4) x1_b = LN(x + P0 + P1 + b_out)
  ln_fuse<0,0><<<dim3(1024), blk, 0, stream>>>(
      qkv + 1024, qkv + 2048, 3072, x, b_out, ln1_g, ln1_b, x1_b);
  // 5) h = gelu(x1 @ w1^T + b1)                     [4096,4096]
  gemm_bt<1,0><<<dim3(32, 32, 1), blk, 0, stream>>>(
      x1_b, 1024, w1_b, 1024, b1, nullptr, 0, h, 4096, 0, 4096, 4096, 1024);
  // 6) split-K=2: P0/P1 = h @ w2^T partials
  gemm_bt<0,0><<<dim3(8, 32, 2), blk, 0, stream>>>(
      h, 4096, w2_b, 4096, nullptr, nullptr, 0,
      P0, 1024, 8388608, 4096, 1024, 2048);
  // 7) out(fp32) = LN(x1 + P0 + P1 + b2)
  ln_fuse<1,1><<<dim3(1024), blk, 0, stream>>>(
      P0, P1, 1024, x1_b, b2, ln2_g, ln2_b, out);
}

// Round 7
// 278.320 us; speedup vs baseline: 1.0264x; 1.0029x over previous
//
#include <hip/hip_runtime.h>
#include <hip/hip_bf16.h>
#include <math.h>

typedef __hip_bfloat16 bf16;
typedef __attribute__((ext_vector_type(8))) short bf16x8;
typedef __attribute__((ext_vector_type(4))) short bf16x4;
typedef __attribute__((ext_vector_type(4))) float f32x4;

#define GPTR(p) ((const __attribute__((address_space(1))) void*)(p))
#define LPTR(p) ((__attribute__((address_space(3))) void*)(p))

__device__ __forceinline__ float b2f(short s) {
  unsigned int u = ((unsigned int)(unsigned short)s) << 16;
  float f; __builtin_memcpy(&f, &u, 4); return f;
}

// ---------------------------------------------------------------------------
// Merged fp32 -> bf16 conversion for all 5 MFMA operand tensors (1 dispatch).
// r7: 4096 blocks x 4 chunks (was 16384 x 1): same coalesced float4->ushort4
// per-lane pattern, 4x work per block -> fewer block-scheduling rounds (G11).
// ---------------------------------------------------------------------------
__global__ __launch_bounds__(256) void cvt_all(
    const float* __restrict__ x,    const float* __restrict__ w_in,
    const float* __restrict__ w_out,const float* __restrict__ w1,
    const float* __restrict__ w2,
    bf16* __restrict__ xb,   bf16* __restrict__ winb, bf16* __restrict__ woutb,
    bf16* __restrict__ w1b,  bf16* __restrict__ w2b)
{
  const int b = blockIdx.x;            // 0..4095
  const float* in; bf16* out; int base;
  if      (b < 1024) { in = x;     out = xb;    base = 0; }
  else if (b < 1792) { in = w_in;  out = winb;  base = 1024; }
  else if (b < 2048) { in = w_out; out = woutb; base = 1792; }
  else if (b < 3072) { in = w1;    out = w1b;   base = 2048; }
  else               { in = w2;    out = w2b;   base = 3072; }
  const int s0 = (b - base) * 4;       // 4 consecutive 1024-float spans
  #pragma unroll
  for (int it = 0; it < 4; ++it) {
    const int i = ((s0 + it) * 256 + threadIdx.x) * 4;
    const float4 f = *(const float4*)(in + i);
    ushort4 u;
    u.x = __bfloat16_as_ushort(__float2bfloat16(f.x));
    u.y = __bfloat16_as_ushort(__float2bfloat16(f.y));
    u.z = __bfloat16_as_ushort(__float2bfloat16(f.z));
    u.w = __bfloat16_as_ushort(__float2bfloat16(f.w));
    *(ushort4*)(out + i) = u;
  }
}

__device__ __forceinline__ float gelu_fast(float v) {
  const float u  = 1.5957691216f * (v + 0.044715f * v * v * v);
  const float e  = __expf(u);
  return v * e / (e + 1.0f);
}

// ---------------------------------------------------------------------------
// GEMM: C[M,N](bf16) = A[M,K](lda) * B[N,K]^T(ldb) [+ bias(fp32)] with
// optional fast-GELU epilogue and split-K via z. 128x128 tile, BK=64,
// 4 waves (2x2), 4x4 mfma_f32_16x16x32_bf16 per wave. XOR chunk swizzle ->
// 2-way LDS conflicts (free). __launch_bounds__(256,4) -> 4 blocks/CU.
// T1 XCD swizzle (m204) ON for every call: r3/r4/r5 A/B showed removing it
// costs +6.6us on GEMM5 even though FETCH improves (37 vs 58 MB) — the
// kernel is latency- not HBM-bound; XCD-private A-panels win.
// Epilogue ni-innermost (r3): WRITE_SIZE at ideal (52.9 -> 32.8 MB).
// ---------------------------------------------------------------------------
template<int GELU, int RESID>   // RESID: 0 none, 1 fp32, 2 bf16
__global__ __launch_bounds__(256, 4) void gemm_bt(
    const bf16* __restrict__ A, int lda,
    const bf16* __restrict__ B, int ldb,
    const float* __restrict__ bias,
    const void* __restrict__ Rv, int ldr,
    bf16* __restrict__ C, int ldc, long czstride,
    int M, int N, int kchunk)
{
  __shared__ __align__(16) bf16 As[128 * 64];
  __shared__ __align__(16) bf16 Bs[128 * 64];

  const int t    = threadIdx.x;
  const int lane = t & 63;
  const int w    = t >> 6;
  const int wm   = w >> 1;
  const int wn   = w & 1;
  const int lr   = lane & 15;
  const int lq   = lane >> 4;

  // T1: bijective XCD swizzle (m204); x fastest within each XCD's wid range.
  const int gx   = gridDim.x, gy = gridDim.y;
  const int nwg  = gx * gy * gridDim.z;
  const int orig = blockIdx.x + gx * (blockIdx.y + gy * blockIdx.z);
  const int qq   = nwg >> 3, rr = nwg & 7;
  const int xcd  = orig & 7;
  const int wid  = (xcd < rr ? xcd * (qq + 1) : rr * (qq + 1) + (xcd - rr) * qq)
                 + (orig >> 3);
  const int n0 = (wid % gx) * 128;
  const int m0 = ((wid / gx) % gy) * 128;
  const int kz = wid / (gx * gy);

  A += (size_t)kz * kchunk;
  B += (size_t)kz * kchunk;
  C += (size_t)kz * czstride;

  f32x4 acc[4][4];
  #pragma unroll
  for (int mi = 0; mi < 4; ++mi)
    #pragma unroll
    for (int ni = 0; ni < 4; ++ni)
      acc[mi][ni] = (f32x4){0.f, 0.f, 0.f, 0.f};

  const int wbase = (t & ~63) * 8;

  for (int k0 = 0; k0 < kchunk; k0 += 64) {
    #pragma unroll
    for (int it = 0; it < 4; ++it) {
      const int c    = it * 256 + t;
      const int row  = c >> 3;
      const int csw  = ((c & 7) ^ (row & 7)) << 3;
      const bf16* ga = A + (size_t)(m0 + row) * lda + k0 + csw;
      const bf16* gb = B + (size_t)(n0 + row) * ldb + k0 + csw;
      __builtin_amdgcn_global_load_lds(GPTR(ga), LPTR(&As[it * 2048 + wbase]), 16, 0, 0);
      __builtin_amdgcn_global_load_lds(GPTR(gb), LPTR(&Bs[it * 2048 + wbase]), 16, 0, 0);
    }
    __syncthreads();

    #pragma unroll
    for (int ks = 0; ks < 2; ++ks) {
      const int swz = (((ks * 4 + lq) ^ (lr & 7)) << 3);
      bf16x8 af[4], bfr[4];
      #pragma unroll
      for (int mi = 0; mi < 4; ++mi)
        af[mi] = *(const bf16x8*)&As[(wm * 64 + mi * 16 + lr) * 64 + swz];
      #pragma unroll
      for (int ni = 0; ni < 4; ++ni)
        bfr[ni] = *(const bf16x8*)&Bs[(wn * 64 + ni * 16 + lr) * 64 + swz];
      #pragma unroll
      for (int mi = 0; mi < 4; ++mi)
        #pragma unroll
        for (int ni = 0; ni < 4; ++ni)
          acc[mi][ni] = __builtin_amdgcn_mfma_f32_16x16x32_bf16(af[mi], bfr[ni], acc[mi][ni], 0, 0, 0);
    }
    __syncthreads();
  }

  // Epilogue, ni innermost: per (mi,i) the 4 stores cover one row's 128
  // contiguous cols back-to-back (write-combine friendly).
  float bvv[4];
  #pragma unroll
  for (int ni = 0; ni < 4; ++ni)
    bvv[ni] = bias ? bias[n0 + wn * 64 + ni * 16 + lr] : 0.f;
  #pragma unroll
  for (int mi = 0; mi < 4; ++mi) {
    const int rowb = m0 + wm * 64 + mi * 16 + lq * 4;
    #pragma unroll
    for (int i = 0; i < 4; ++i) {
      const size_t rb = (size_t)(rowb + i);
      #pragma unroll
      for (int ni = 0; ni < 4; ++ni) {
        const int col = n0 + wn * 64 + ni * 16 + lr;
        float v = acc[mi][ni][i] + bvv[ni];
        if (GELU) v = gelu_fast(v);
        if (RESID == 1) v += ((const float*)Rv)[rb * ldr + col];
        if (RESID == 2) v += __bfloat162float(((const bf16*)Rv)[rb * ldr + col]);
        C[rb * ldc + col] = __float2bfloat16(v);
      }
    }
  }
}

// ---------------------------------------------------------------------------
// Window-5 causal attention, one WAVE per token. lane = h*4 + c. Scores stay
// register-local; in-place into q-cols (wave t is the sole reader of q[t]).
// XCD grouping (m204, 1024 % 8 == 0): adjacent blocks (= adjacent tokens)
// land on the same XCD -> 5-token window K/V reuse is L2-local.
// ---------------------------------------------------------------------------
__global__ __launch_bounds__(256) void attn_win(bf16* __restrict__ qkv)
{
  const int lane = threadIdx.x & 63;
  const int nb   = gridDim.x;                    // 1024, divisible by 8
  const int bq   = nb >> 3;
  const int bid  = (blockIdx.x & 7) * bq + (blockIdx.x >> 3);
  const int tk   = bid * 4 + (threadIdx.x >> 6);          // token 0..4095
  const int s    = tk & 2047;                             // pos in sequence
  const int doff = (lane >> 2) * 64 + (lane & 3) * 16;    // h*64 + c*16

  const size_t row = (size_t)tk * 3072;

  bf16x8 qa = *(const bf16x8*)&qkv[row + doff];
  bf16x8 qb = *(const bf16x8*)&qkv[row + doff + 8];
  float qf[16];
  #pragma unroll
  for (int e = 0; e < 8; ++e) { qf[e] = b2f(qa[e]); qf[8 + e] = b2f(qb[e]); }

  const int W = (s + 1 < 5) ? (s + 1) : 5;
  float p[5];
  #pragma unroll
  for (int j = 0; j < 5; ++j) {
    const int jc = (j < W) ? j : 0;                       // clamped (valid addr)
    const size_t kr = row - (size_t)jc * 3072 + 1024;
    bf16x8 ka = *(const bf16x8*)&qkv[kr + doff];
    bf16x8 kb = *(const bf16x8*)&qkv[kr + doff + 8];
    float d = 0.f;
    #pragma unroll
    for (int e = 0; e < 8; ++e) d += qf[e] * b2f(ka[e]);
    #pragma unroll
    for (int e = 0; e < 8; ++e) d += qf[8 + e] * b2f(kb[e]);
    d += __shfl_xor(d, 1);
    d += __shfl_xor(d, 2);
    p[j] = (j < W) ? d * 0.125f : -1e30f;                 // 1/sqrt(64); mask
  }

  float mx = fmaxf(fmaxf(fmaxf(p[0], p[1]), fmaxf(p[2], p[3])), p[4]);
  float sum = 0.f;
  #pragma unroll
  for (int j = 0; j < 5; ++j) { p[j] = __expf(p[j] - mx); sum += p[j]; }
  const float inv = 1.f / sum;

  float o[16];
  #pragma unroll
  for (int e = 0; e < 16; ++e) o[e] = 0.f;
  #pragma unroll
  for (int j = 0; j < 5; ++j) {
    const int jc = (j < W) ? j : 0;
    const size_t vr = row - (size_t)jc * 3072 + 2048;
    bf16x8 va = *(const bf16x8*)&qkv[vr + doff];
    bf16x8 vb = *(const bf16x8*)&qkv[vr + doff + 8];
    #pragma unroll
    for (int e = 0; e < 8; ++e) { o[e] += p[j] * b2f(va[e]); o[8 + e] += p[j] * b2f(vb[e]); }
  }

  bf16x8 oa, ob;
  #pragma unroll
  for (int e = 0; e < 8; ++e) {
    oa[e] = (short)__bfloat16_as_ushort(__float2bfloat16(o[e] * inv));
    ob[e] = (short)__bfloat16_as_ushort(__float2bfloat16(o[8 + e] * inv));
  }
  *(bf16x8*)&qkv[row + doff]     = oa;
  *(bf16x8*)&qkv[row + doff + 8] = ob;
}

// ---------------------------------------------------------------------------
// Fused split-K reduce + residual + bias + LayerNorm over dim=1024.
// Partition: lane L owns elems {256q + 4L + j, q,j in 0..3}. EVERY array
// access is a fully-coalesced 64-lane vector op: bf16 as bf16x4 (8 B/lane),
// fp32 + bias/g/bt as float4 (16 B/lane). r5's lane-contiguous variant
// scattered bias/g/bt at stride 64 B and cost ~+11 us — do not regress.
// Reductions are partition-agnostic (full 64-lane shfl butterflies).
// ---------------------------------------------------------------------------
template<int OUTF32, int RESBF16>
__global__ __launch_bounds__(256) void ln_fuse(
    const bf16* __restrict__ P0, const bf16* __restrict__ P1, int ldp,
    const void* __restrict__ Rv,
    const float* __restrict__ bias,
    const float* __restrict__ g, const float* __restrict__ bt,
    void* __restrict__ outv)
{
  const int tk   = blockIdx.x * 4 + (threadIdx.x >> 6);
  const int lane = threadIdx.x & 63;
  const int e0   = lane * 4;                      // chunk base within 256-span
  const size_t bp = (size_t)tk * ldp + e0;
  const size_t bo = (size_t)tk * 1024 + e0;

  float v[16];
  float sum = 0.f;
  #pragma unroll
  for (int q = 0; q < 4; ++q) {
    const bf16x4 p0 = *(const bf16x4*)&P0[bp + 256 * q];
    const bf16x4 p1 = *(const bf16x4*)&P1[bp + 256 * q];
    const float4 bs = *(const float4*)&bias[e0 + 256 * q];
    const float bsa[4] = {bs.x, bs.y, bs.z, bs.w};
    float ra[4];
    if (RESBF16) {
      const bf16x4 r = *(const bf16x4*)&((const bf16*)Rv)[bo + 256 * q];
      #pragma unroll
      for (int j = 0; j < 4; ++j) ra[j] = b2f(r[j]);
    } else {
      const float4 r = *(const float4*)&((const float*)Rv)[bo + 256 * q];
      ra[0] = r.x; ra[1] = r.y; ra[2] = r.z; ra[3] = r.w;
    }
    #pragma unroll
    for (int j = 0; j < 4; ++j) {
      const float tv = b2f(p0[j]) + b2f(p1[j]) + bsa[j] + ra[j];
      v[q * 4 + j] = tv;
      sum += tv;
    }
  }
  #pragma unroll
  for (int d = 1; d < 64; d <<= 1) sum += __shfl_xor(sum, d);
  const float mu = sum * (1.f / 1024.f);

  float sq = 0.f;
  #pragma unroll
  for (int i = 0; i < 16; ++i) { const float dv = v[i] - mu; sq += dv * dv; }
  #pragma unroll
  for (int d = 1; d < 64; d <<= 1) sq += __shfl_xor(sq, d);
  const float rstd = rsqrtf(sq * (1.f / 1024.f) + 1e-5f);

  #pragma unroll
  for (int q = 0; q < 4; ++q) {
    const float4 gv = *(const float4*)&g[e0 + 256 * q];
    const float4 bv = *(const float4*)&bt[e0 + 256 * q];
    const float ga[4] = {gv.x, gv.y, gv.z, gv.w};
    const float ba[4] = {bv.x, bv.y, bv.z, bv.w};
    float ov[4];
    #pragma unroll
    for (int j = 0; j < 4; ++j)
      ov[j] = (v[q * 4 + j] - mu) * rstd * ga[j] + ba[j];
    if (OUTF32) {
      float4 f; f.x = ov[0]; f.y = ov[1]; f.z = ov[2]; f.w = ov[3];
      *(float4*)&((float*)outv)[bo + 256 * q] = f;
    } else {
      bf16x4 ob;
      #pragma unroll
      for (int j = 0; j < 4; ++j)
        ob[j] = (short)__bfloat16_as_ushort(__float2bfloat16(ov[j]));
      *(bf16x4*)&((bf16*)outv)[bo + 256 * q] = ob;
    }
  }
}

// ---------------------------------------------------------------------------
// WS layout (72 MB):
//   0        : qkv [4096,3072] bf16 / phase2: h [4096,4096]
//   33554432 : x_b [4096,1024] -> GEMM6 partial P0
//   41943040 : x1_b [4096,1024]
//   50331648 : w1_b [4096,1024] -> GEMM6 partial P1
//   58720256 : w2_b [1024,4096]
//   67108864 : w_in_b [3072,1024]
//   73400320 : w_out_b [1024,1024]
// ---------------------------------------------------------------------------
extern "C" void kernel_launch(void* const* d_in, const int* in_sizes, int n_in,
                              void* d_out, int out_size, void* d_ws, size_t ws_size,
                              hipStream_t stream)
{
  const float* x     = (const float*)d_in[0];
  const float* w_in  = (const float*)d_in[1];
  const float* b_in  = (const float*)d_in[2];
  const float* w_out = (const float*)d_in[3];
  const float* b_out = (const float*)d_in[4];
  const float* ln1_g = (const float*)d_in[5];
  const float* ln1_b = (const float*)d_in[6];
  const float* ln2_g = (const float*)d_in[7];
  const float* ln2_b = (const float*)d_in[8];
  const float* w1    = (const float*)d_in[9];
  const float* b1    = (const float*)d_in[10];
  const float* w2    = (const float*)d_in[11];
  const float* b2    = (const float*)d_in[12];
  float* out = (float*)d_out;

  char* ws = (char*)d_ws;
  bf16* qkv     = (bf16*)(ws);
  bf16* h       = (bf16*)(ws);
  bf16* x_b     = (bf16*)(ws + 33554432);
  bf16* x1_b    = (bf16*)(ws + 41943040);
  bf16* w1_b    = (bf16*)(ws + 50331648);
  bf16* w2_b    = (bf16*)(ws + 58720256);
  bf16* w_in_b  = (bf16*)(ws + 67108864);
  bf16* w_out_b = (bf16*)(ws + 73400320);
  bf16* P0      = x_b;
  bf16* P1      = w1_b;

  const dim3 blk(256);

  // 0) fp32 -> bf16 operand conversion (single dispatch, 4096 blocks)
  cvt_all<<<dim3(4096), blk, 0, stream>>>(x, w_in, w_out, w1, w2,
                                          x_b, w_in_b, w_out_b, w1_b, w2_b);

  // 1) qkv = x @ w_in^T + b_in                      [4096,3072]
  gemm_bt<0,0><<<dim3(24, 32, 1), blk, 0, stream>>>(
      x_b, 1024, w_in_b, 1024, b_in, nullptr, 0, qkv, 3072, 0, 4096, 3072, 1024);
  // 2) windowed causal attention, in-place into q-cols (wave per token)
  attn_win<<<dim3(1024), blk, 0, stream>>>(qkv);
  // 3) split-K=2: k-cols/v-cols = attn @ w_out^T partials
  gemm_bt<0,0><<<dim3(8, 32, 2), blk, 0, stream>>>(
      qkv, 3072, w_out_b, 1024, nullptr, nullptr, 0,
      qkv + 1024, 3072, 1024, 4096, 1024, 512);
  // 4) x1_b = LN(x + P0 + P1 + b_out)
  ln_fuse<0,0><<<dim3(1024), blk, 0, stream>>>(
      qkv + 1024, qkv + 2048, 3072, x, b_out, ln1_g, ln1_b, x1_b);
  // 5) h = gelu(x1 @ w1^T + b1)                     [4096,4096]
  gemm_bt<1,0><<<dim3(32, 32, 1), blk, 0, stream>>>(
      x1_b, 1024, w1_b, 1024, b1, nullptr, 0, h, 4096, 0, 4096, 4096, 1024);
  // 6) split-K=2: P0/P1 = h @ w2^T partials
  gemm_bt<0,0><<<dim3(8, 32, 2), blk, 0, stream>>>(
      h, 4096, w2_b, 4096, nullptr, nullptr, 0,
      P0, 1024, 8388608, 4096, 1024, 2048);
  // 7) out(fp32) = LN(x1 + P0 + P1 + b2)
  ln_fuse<1,1><<<dim3(1024), blk, 0, stream>>>(
      P0, P1, 1024, x1_b, b2, ln2_g, ln2_b, out);
}

// Round 8
// 262.746 us; speedup vs baseline: 1.0873x; 1.0593x over previous
//
#include <hip/hip_runtime.h>
#include <hip/hip_bf16.h>
#include <math.h>

typedef __hip_bfloat16 bf16;
typedef __attribute__((ext_vector_type(8))) short bf16x8;
typedef __attribute__((ext_vector_type(4))) short bf16x4;
typedef __attribute__((ext_vector_type(4))) float f32x4;

#define GPTR(p) ((const __attribute__((address_space(1))) void*)(p))
#define LPTR(p) ((__attribute__((address_space(3))) void*)(p))

__device__ __forceinline__ float b2f(short s) {
  unsigned int u = ((unsigned int)(unsigned short)s) << 16;
  float f; __builtin_memcpy(&f, &u, 4); return f;
}

// ---------------------------------------------------------------------------
// Merged fp32 -> bf16 conversion for all 5 MFMA operand tensors (1 dispatch).
// 4096 blocks x 4 chunks, coalesced float4 -> ushort4.
// ---------------------------------------------------------------------------
__global__ __launch_bounds__(256) void cvt_all(
    const float* __restrict__ x,    const float* __restrict__ w_in,
    const float* __restrict__ w_out,const float* __restrict__ w1,
    const float* __restrict__ w2,
    bf16* __restrict__ xb,   bf16* __restrict__ winb, bf16* __restrict__ woutb,
    bf16* __restrict__ w1b,  bf16* __restrict__ w2b)
{
  const int b = blockIdx.x;            // 0..4095
  const float* in; bf16* out; int base;
  if      (b < 1024) { in = x;     out = xb;    base = 0; }
  else if (b < 1792) { in = w_in;  out = winb;  base = 1024; }
  else if (b < 2048) { in = w_out; out = woutb; base = 1792; }
  else if (b < 3072) { in = w1;    out = w1b;   base = 2048; }
  else               { in = w2;    out = w2b;   base = 3072; }
  const int s0 = (b - base) * 4;       // 4 consecutive 1024-float spans
  #pragma unroll
  for (int it = 0; it < 4; ++it) {
    const int i = ((s0 + it) * 256 + threadIdx.x) * 4;
    const float4 f = *(const float4*)(in + i);
    ushort4 u;
    u.x = __bfloat16_as_ushort(__float2bfloat16(f.x));
    u.y = __bfloat16_as_ushort(__float2bfloat16(f.y));
    u.z = __bfloat16_as_ushort(__float2bfloat16(f.z));
    u.w = __bfloat16_as_ushort(__float2bfloat16(f.w));
    *(ushort4*)(out + i) = u;
  }
}

__device__ __forceinline__ float gelu_fast(float v) {
  const float u  = 1.5957691216f * (v + 0.044715f * v * v * v);
  const float e  = __expf(u);
  return v * e / (e + 1.0f);
}

// ---------------------------------------------------------------------------
// GEMM: C[M,N](bf16) = A[M,K](lda) * B[N,K]^T(ldb) [+ bias(fp32)] with
// optional fast-GELU epilogue and split-K via z. 128x128 tile, BK=64,
// 4 waves (2x2), 4x4 mfma_f32_16x16x32_bf16 per wave. XOR chunk swizzle ->
// 2-way LDS conflicts (free). __launch_bounds__(256,4) -> 4 blocks/CU.
// CH (XCD mapping; r3/r4/r5 A/B proved XCD-private operand panels beat
// default round-robin by 6.6us on GEMM5 despite higher FETCH):
//   CH=0: m204 row-chunks, x fastest (flat grids, GEMM3/6: B fully
//         L2-resident per XCD).
//   CH=1: 2D rectangle per XCD (HK chiplet_transform_chunked analog):
//         XCD x owns rect (x&1, x>>1) of (gx/2)x(gy/4) tiles, column-major
//         inside. Private A AND B panels, ~2.25MB working set < 4MB L2.
//         GEMM5: 9MB/XCD streamed -> 6MB. Requires gx%2==0, gy%4==0, gz==1,
//         nwg%8==0 (square grids, GEMM1/5).
// Epilogue ni-innermost (r3): WRITE_SIZE at ideal (52.9 -> 32.8 MB).
// ---------------------------------------------------------------------------
template<int GELU, int RESID, int CH>   // RESID: 0 none, 1 fp32, 2 bf16
__global__ __launch_bounds__(256, 4) void gemm_bt(
    const bf16* __restrict__ A, int lda,
    const bf16* __restrict__ B, int ldb,
    const float* __restrict__ bias,
    const void* __restrict__ Rv, int ldr,
    bf16* __restrict__ C, int ldc, long czstride,
    int M, int N, int kchunk)
{
  __shared__ __align__(16) bf16 As[128 * 64];
  __shared__ __align__(16) bf16 Bs[128 * 64];

  const int t    = threadIdx.x;
  const int lane = t & 63;
  const int w    = t >> 6;
  const int wm   = w >> 1;
  const int wn   = w & 1;
  const int lr   = lane & 15;
  const int lq   = lane >> 4;

  const int gx   = gridDim.x, gy = gridDim.y;
  const int nwg  = gx * gy * gridDim.z;
  const int orig = blockIdx.x + gx * (blockIdx.y + gy * blockIdx.z);
  int n0, m0, kz;
  if (CH == 1) {
    // nwg % 8 == 0: XCD x gets origs {x, x+8, ...} -> lid contiguous 0..cpx-1
    const int xcd = orig & 7;
    const int lid = orig >> 3;
    const int w2 = gx >> 1, h2 = gy >> 2;      // rect dims in tiles
    const int rx = xcd & 1, ry = xcd >> 1;     // 2 x 4 rectangle layout
    const int c  = lid / h2;                   // column-major inside rect
    const int r  = lid - c * h2;
    n0 = (rx * w2 + c) * 128;
    m0 = (ry * h2 + r) * 128;
    kz = 0;
  } else {
    const int qq   = nwg >> 3, rr = nwg & 7;
    const int xcd  = orig & 7;
    const int wid  = (xcd < rr ? xcd * (qq + 1) : rr * (qq + 1) + (xcd - rr) * qq)
                   + (orig >> 3);
    n0 = (wid % gx) * 128;
    m0 = ((wid / gx) % gy) * 128;
    kz = wid / (gx * gy);
  }

  A += (size_t)kz * kchunk;
  B += (size_t)kz * kchunk;
  C += (size_t)kz * czstride;

  f32x4 acc[4][4];
  #pragma unroll
  for (int mi = 0; mi < 4; ++mi)
    #pragma unroll
    for (int ni = 0; ni < 4; ++ni)
      acc[mi][ni] = (f32x4){0.f, 0.f, 0.f, 0.f};

  const int wbase = (t & ~63) * 8;

  for (int k0 = 0; k0 < kchunk; k0 += 64) {
    #pragma unroll
    for (int it = 0; it < 4; ++it) {
      const int c    = it * 256 + t;
      const int row  = c >> 3;
      const int csw  = ((c & 7) ^ (row & 7)) << 3;
      const bf16* ga = A + (size_t)(m0 + row) * lda + k0 + csw;
      const bf16* gb = B + (size_t)(n0 + row) * ldb + k0 + csw;
      __builtin_amdgcn_global_load_lds(GPTR(ga), LPTR(&As[it * 2048 + wbase]), 16, 0, 0);
      __builtin_amdgcn_global_load_lds(GPTR(gb), LPTR(&Bs[it * 2048 + wbase]), 16, 0, 0);
    }
    __syncthreads();

    #pragma unroll
    for (int ks = 0; ks < 2; ++ks) {
      const int swz = (((ks * 4 + lq) ^ (lr & 7)) << 3);
      bf16x8 af[4], bfr[4];
      #pragma unroll
      for (int mi = 0; mi < 4; ++mi)
        af[mi] = *(const bf16x8*)&As[(wm * 64 + mi * 16 + lr) * 64 + swz];
      #pragma unroll
      for (int ni = 0; ni < 4; ++ni)
        bfr[ni] = *(const bf16x8*)&Bs[(wn * 64 + ni * 16 + lr) * 64 + swz];
      #pragma unroll
      for (int mi = 0; mi < 4; ++mi)
        #pragma unroll
        for (int ni = 0; ni < 4; ++ni)
          acc[mi][ni] = __builtin_amdgcn_mfma_f32_16x16x32_bf16(af[mi], bfr[ni], acc[mi][ni], 0, 0, 0);
    }
    __syncthreads();
  }

  // Epilogue, ni innermost: per (mi,i) the 4 stores cover one row's 128
  // contiguous cols back-to-back (write-combine friendly).
  float bvv[4];
  #pragma unroll
  for (int ni = 0; ni < 4; ++ni)
    bvv[ni] = bias ? bias[n0 + wn * 64 + ni * 16 + lr] : 0.f;
  #pragma unroll
  for (int mi = 0; mi < 4; ++mi) {
    const int rowb = m0 + wm * 64 + mi * 16 + lq * 4;
    #pragma unroll
    for (int i = 0; i < 4; ++i) {
      const size_t rb = (size_t)(rowb + i);
      #pragma unroll
      for (int ni = 0; ni < 4; ++ni) {
        const int col = n0 + wn * 64 + ni * 16 + lr;
        float v = acc[mi][ni][i] + bvv[ni];
        if (GELU) v = gelu_fast(v);
        if (RESID == 1) v += ((const float*)Rv)[rb * ldr + col];
        if (RESID == 2) v += __bfloat162float(((const bf16*)Rv)[rb * ldr + col]);
        C[rb * ldc + col] = __float2bfloat16(v);
      }
    }
  }
}

// ---------------------------------------------------------------------------
// Window-5 causal attention, one WAVE per token. lane = h*4 + c. Scores stay
// register-local; in-place into q-cols (wave t is the sole reader of q[t]).
// XCD grouping (m204): adjacent blocks (= adjacent tokens) share an XCD ->
// 5-token window K/V reuse is L2-local.
// ---------------------------------------------------------------------------
__global__ __launch_bounds__(256) void attn_win(bf16* __restrict__ qkv)
{
  const int lane = threadIdx.x & 63;
  const int nb   = gridDim.x;                    // 1024, divisible by 8
  const int bq   = nb >> 3;
  const int bid  = (blockIdx.x & 7) * bq + (blockIdx.x >> 3);
  const int tk   = bid * 4 + (threadIdx.x >> 6);          // token 0..4095
  const int s    = tk & 2047;                             // pos in sequence
  const int doff = (lane >> 2) * 64 + (lane & 3) * 16;    // h*64 + c*16

  const size_t row = (size_t)tk * 3072;

  bf16x8 qa = *(const bf16x8*)&qkv[row + doff];
  bf16x8 qb = *(const bf16x8*)&qkv[row + doff + 8];
  float qf[16];
  #pragma unroll
  for (int e = 0; e < 8; ++e) { qf[e] = b2f(qa[e]); qf[8 + e] = b2f(qb[e]); }

  const int W = (s + 1 < 5) ? (s + 1) : 5;
  float p[5];
  #pragma unroll
  for (int j = 0; j < 5; ++j) {
    const int jc = (j < W) ? j : 0;                       // clamped (valid addr)
    const size_t kr = row - (size_t)jc * 3072 + 1024;
    bf16x8 ka = *(const bf16x8*)&qkv[kr + doff];
    bf16x8 kb = *(const bf16x8*)&qkv[kr + doff + 8];
    float d = 0.f;
    #pragma unroll
    for (int e = 0; e < 8; ++e) d += qf[e] * b2f(ka[e]);
    #pragma unroll
    for (int e = 0; e < 8; ++e) d += qf[8 + e] * b2f(kb[e]);
    d += __shfl_xor(d, 1);
    d += __shfl_xor(d, 2);
    p[j] = (j < W) ? d * 0.125f : -1e30f;                 // 1/sqrt(64); mask
  }

  float mx = fmaxf(fmaxf(fmaxf(p[0], p[1]), fmaxf(p[2], p[3])), p[4]);
  float sum = 0.f;
  #pragma unroll
  for (int j = 0; j < 5; ++j) { p[j] = __expf(p[j] - mx); sum += p[j]; }
  const float inv = 1.f / sum;

  float o[16];
  #pragma unroll
  for (int e = 0; e < 16; ++e) o[e] = 0.f;
  #pragma unroll
  for (int j = 0; j < 5; ++j) {
    const int jc = (j < W) ? j : 0;
    const size_t vr = row - (size_t)jc * 3072 + 2048;
    bf16x8 va = *(const bf16x8*)&qkv[vr + doff];
    bf16x8 vb = *(const bf16x8*)&qkv[vr + doff + 8];
    #pragma unroll
    for (int e = 0; e < 8; ++e) { o[e] += p[j] * b2f(va[e]); o[8 + e] += p[j] * b2f(vb[e]); }
  }

  bf16x8 oa, ob;
  #pragma unroll
  for (int e = 0; e < 8; ++e) {
    oa[e] = (short)__bfloat16_as_ushort(__float2bfloat16(o[e] * inv));
    ob[e] = (short)__bfloat16_as_ushort(__float2bfloat16(o[8 + e] * inv));
  }
  *(bf16x8*)&qkv[row + doff]     = oa;
  *(bf16x8*)&qkv[row + doff + 8] = ob;
}

// ---------------------------------------------------------------------------
// Fused split-K reduce + residual + bias + LayerNorm over dim=1024.
// Partition: lane L owns elems {256q + 4L + j, q,j in 0..3}. EVERY array
// access is a fully-coalesced 64-lane vector op: bf16 as bf16x4 (8 B/lane),
// fp32 + bias/g/bt as float4 (16 B/lane). r5's lane-contiguous variant
// scattered bias/g/bt at stride 64 B and cost ~+11 us — do not regress.
// Reductions are partition-agnostic (full 64-lane shfl butterflies).
// ---------------------------------------------------------------------------
template<int OUTF32, int RESBF16>
__global__ __launch_bounds__(256) void ln_fuse(
    const bf16* __restrict__ P0, const bf16* __restrict__ P1, int ldp,
    const void* __restrict__ Rv,
    const float* __restrict__ bias,
    const float* __restrict__ g, const float* __restrict__ bt,
    void* __restrict__ outv)
{
  const int tk   = blockIdx.x * 4 + (threadIdx.x >> 6);
  const int lane = threadIdx.x & 63;
  const int e0   = lane * 4;                      // chunk base within 256-span
  const size_t bp = (size_t)tk * ldp + e0;
  const size_t bo = (size_t)tk * 1024 + e0;

  float v[16];
  float sum = 0.f;
  #pragma unroll
  for (int q = 0; q < 4; ++q) {
    const bf16x4 p0 = *(const bf16x4*)&P0[bp + 256 * q];
    const bf16x4 p1 = *(const bf16x4*)&P1[bp + 256 * q];
    const float4 bs = *(const float4*)&bias[e0 + 256 * q];
    const float bsa[4] = {bs.x, bs.y, bs.z, bs.w};
    float ra[4];
    if (RESBF16) {
      const bf16x4 r = *(const bf16x4*)&((const bf16*)Rv)[bo + 256 * q];
      #pragma unroll
      for (int j = 0; j < 4; ++j) ra[j] = b2f(r[j]);
    } else {
      const float4 r = *(const float4*)&((const float*)Rv)[bo + 256 * q];
      ra[0] = r.x; ra[1] = r.y; ra[2] = r.z; ra[3] = r.w;
    }
    #pragma unroll
    for (int j = 0; j < 4; ++j) {
      const float tv = b2f(p0[j]) + b2f(p1[j]) + bsa[j] + ra[j];
      v[q * 4 + j] = tv;
      sum += tv;
    }
  }
  #pragma unroll
  for (int d = 1; d < 64; d <<= 1) sum += __shfl_xor(sum, d);
  const float mu = sum * (1.f / 1024.f);

  float sq = 0.f;
  #pragma unroll
  for (int i = 0; i < 16; ++i) { const float dv = v[i] - mu; sq += dv * dv; }
  #pragma unroll
  for (int d = 1; d < 64; d <<= 1) sq += __shfl_xor(sq, d);
  const float rstd = rsqrtf(sq * (1.f / 1024.f) + 1e-5f);

  #pragma unroll
  for (int q = 0; q < 4; ++q) {
    const float4 gv = *(const float4*)&g[e0 + 256 * q];
    const float4 bv = *(const float4*)&bt[e0 + 256 * q];
    const float ga[4] = {gv.x, gv.y, gv.z, gv.w};
    const float ba[4] = {bv.x, bv.y, bv.z, bv.w};
    float ov[4];
    #pragma unroll
    for (int j = 0; j < 4; ++j)
      ov[j] = (v[q * 4 + j] - mu) * rstd * ga[j] + ba[j];
    if (OUTF32) {
      float4 f; f.x = ov[0]; f.y = ov[1]; f.z = ov[2]; f.w = ov[3];
      *(float4*)&((float*)outv)[bo + 256 * q] = f;
    } else {
      bf16x4 ob;
      #pragma unroll
      for (int j = 0; j < 4; ++j)
        ob[j] = (short)__bfloat16_as_ushort(__float2bfloat16(ov[j]));
      *(bf16x4*)&((bf16*)outv)[bo + 256 * q] = ob;
    }
  }
}

// ---------------------------------------------------------------------------
// WS layout (72 MB):
//   0        : qkv [4096,3072] bf16 / phase2: h [4096,4096]
//   33554432 : x_b [4096,1024] -> GEMM6 partial P0
//   41943040 : x1_b [4096,1024]
//   50331648 : w1_b [4096,1024] -> GEMM6 partial P1
//   58720256 : w2_b [1024,4096]
//   67108864 : w_in_b [3072,1024]
//   73400320 : w_out_b [1024,1024]
// ---------------------------------------------------------------------------
extern "C" void kernel_launch(void* const* d_in, const int* in_sizes, int n_in,
                              void* d_out, int out_size, void* d_ws, size_t ws_size,
                              hipStream_t stream)
{
  const float* x     = (const float*)d_in[0];
  const float* w_in  = (const float*)d_in[1];
  const float* b_in  = (const float*)d_in[2];
  const float* w_out = (const float*)d_in[3];
  const float* b_out = (const float*)d_in[4];
  const float* ln1_g = (const float*)d_in[5];
  const float* ln1_b = (const float*)d_in[6];
  const float* ln2_g = (const float*)d_in[7];
  const float* ln2_b = (const float*)d_in[8];
  const float* w1    = (const float*)d_in[9];
  const float* b1    = (const float*)d_in[10];
  const float* w2    = (const float*)d_in[11];
  const float* b2    = (const float*)d_in[12];
  float* out = (float*)d_out;

  char* ws = (char*)d_ws;
  bf16* qkv     = (bf16*)(ws);
  bf16* h       = (bf16*)(ws);
  bf16* x_b     = (bf16*)(ws + 33554432);
  bf16* x1_b    = (bf16*)(ws + 41943040);
  bf16* w1_b    = (bf16*)(ws + 50331648);
  bf16* w2_b    = (bf16*)(ws + 58720256);
  bf16* w_in_b  = (bf16*)(ws + 67108864);
  bf16* w_out_b = (bf16*)(ws + 73400320);
  bf16* P0      = x_b;
  bf16* P1      = w1_b;

  const dim3 blk(256);

  // 0) fp32 -> bf16 operand conversion (single dispatch, 4096 blocks)
  cvt_all<<<dim3(4096), blk, 0, stream>>>(x, w_in, w_out, w1, w2,
                                          x_b, w_in_b, w_out_b, w1_b, w2_b);

  // 1) qkv = x @ w_in^T + b_in          [4096,3072]  (square grid, 2D chunks)
  gemm_bt<0,0,1><<<dim3(24, 32, 1), blk, 0, stream>>>(
      x_b, 1024, w_in_b, 1024, b_in, nullptr, 0, qkv, 3072, 0, 4096, 3072, 1024);
  // 2) windowed causal attention, in-place into q-cols (wave per token)
  attn_win<<<dim3(1024), blk, 0, stream>>>(qkv);
  // 3) split-K=2: k-cols/v-cols = attn @ w_out^T partials (flat, row chunks)
  gemm_bt<0,0,0><<<dim3(8, 32, 2), blk, 0, stream>>>(
      qkv, 3072, w_out_b, 1024, nullptr, nullptr, 0,
      qkv + 1024, 3072, 1024, 4096, 1024, 512);
  // 4) x1_b = LN(x + P0 + P1 + b_out)
  ln_fuse<0,0><<<dim3(1024), blk, 0, stream>>>(
      qkv + 1024, qkv + 2048, 3072, x, b_out, ln1_g, ln1_b, x1_b);
  // 5) h = gelu(x1 @ w1^T + b1)         [4096,4096]  (square grid, 2D chunks)
  gemm_bt<1,0,1><<<dim3(32, 32, 1), blk, 0, stream>>>(
      x1_b, 1024, w1_b, 1024, b1, nullptr, 0, h, 4096, 0, 4096, 4096, 1024);
  // 6) split-K=2: P0/P1 = h @ w2^T partials                (flat, row chunks)
  gemm_bt<0,0,0><<<dim3(8, 32, 2), blk, 0, stream>>>(
      h, 4096, w2_b, 4096, nullptr, nullptr, 0,
      P0, 1024, 8388608, 4096, 1024, 2048);
  // 7) out(fp32) = LN(x1 + P0 + P1 + b2)
  ln_fuse<1,1><<<dim3(1024), blk, 0, stream>>>(
      P0, P1, 1024, x1_b, b2, ln2_g, ln2_b, out);
}